// Round 9
// baseline (254.356 us; speedup 1.0000x reference)
//
#include <hip/hip_runtime.h>

#define B_ 4
#define T_ 2048
#define D_ 1024
#define H_ 16
#define DH_ 64
#define M_ (B_*T_)   // 8192 tokens
#define KP 72        // padded LDS row stride (elements) for flash K/V tiles

typedef __attribute__((ext_vector_type(8))) short short8;       // 8 bf16 (MFMA K=32 A/B frag)
typedef __attribute__((ext_vector_type(4))) float f32x4;        // MFMA C/D frag
typedef __attribute__((ext_vector_type(4))) unsigned short u16x4;
typedef _Float16 half4f __attribute__((ext_vector_type(4)));    // MFMA K=16 f16 A/B frag
typedef __fp16 h2raw __attribute__((ext_vector_type(2)));       // cvt_pkrtz return type

__device__ __forceinline__ unsigned short f2bf(float f) {
  unsigned int u = __float_as_uint(f);
  u += 0x7FFFu + ((u >> 16) & 1u);   // RNE
  return (unsigned short)(u >> 16);
}

__device__ __forceinline__ void async_copy16(const void* g, void* l) {
  __builtin_amdgcn_global_load_lds(
      (const __attribute__((address_space(1))) unsigned int*)(g),
      (__attribute__((address_space(3))) unsigned int*)(l),
      16, 0, 0);
}

__device__ __forceinline__ f32x4 mfma32(short8 a, short8 b, f32x4 c) {
  return __builtin_amdgcn_mfma_f32_16x16x32_bf16(a, b, c, 0, 0, 0);
}
__device__ __forceinline__ f32x4 mfma16h(half4f a, half4f b, f32x4 c) {
  return __builtin_amdgcn_mfma_f32_16x16x16f16(a, b, c, 0, 0, 0);
}

// ---------------- fused fp32 -> bf16 convert (x + 4 weights, one launch) ----------------
#define NX4 (M_*D_/4)
#define NW4 (D_*D_/4)
__global__ __launch_bounds__(256) void cvt_all(
    const float* __restrict__ x,  const float* __restrict__ wq,
    const float* __restrict__ wk, const float* __restrict__ wv,
    const float* __restrict__ wo, unsigned short* __restrict__ xb,
    unsigned short* __restrict__ wqb, unsigned short* __restrict__ wkb,
    unsigned short* __restrict__ wvb, unsigned short* __restrict__ wob) {
  int i = blockIdx.x * 256 + threadIdx.x;
  const float* src; unsigned short* dst; int off;
  if (i < NX4)             { src = x;  dst = xb;  off = i; }
  else if (i < NX4 + NW4)  { src = wq; dst = wqb; off = i - NX4; }
  else if (i < NX4 + 2*NW4){ src = wk; dst = wkb; off = i - NX4 - NW4; }
  else if (i < NX4 + 3*NW4){ src = wv; dst = wvb; off = i - NX4 - 2*NW4; }
  else                     { src = wo; dst = wob; off = i - NX4 - 3*NW4; }
  const float4 v = reinterpret_cast<const float4*>(src)[off];
  u16x4 o;
  o.x = f2bf(v.x); o.y = f2bf(v.y); o.z = f2bf(v.z); o.w = f2bf(v.w);
  reinterpret_cast<u16x4*>(dst)[off] = o;
}

// ---------------- fused QKV projection GEMM (BK=64) ----------------
// grid (64, 24): blockIdx.y -> seg (q/k/v) x 8 column tiles. C = xb @ W^T.
// seg 0: Q bf16, scaled by 1/8*log2(e). seg 1: K bf16. seg 2: V f16 transposed (B,H,DH,T).
// BK=64 halves the per-iter barrier drain count vs BK=32 (16 iters for K=1024).
// LDS 32KB -> 5 blocks/CU (m132's BK=128/64KB regressed to 2 blocks/CU).
__global__ __launch_bounds__(256) void gemm_qkv(
    const unsigned short* __restrict__ A,
    const unsigned short* __restrict__ Wq,
    const unsigned short* __restrict__ Wk,
    const unsigned short* __restrict__ Wv,
    unsigned short* __restrict__ Qo,
    unsigned short* __restrict__ Ko,
    _Float16* __restrict__ Vo) {
  __shared__ __align__(16) unsigned short ldsA[128*64];  // 16 KB
  __shared__ __align__(16) unsigned short ldsB[128*64];  // 16 KB
  const int tid = threadIdx.x;
  const int w = tid >> 6, lane = tid & 63;
  const int quad = lane >> 4, l16 = lane & 15;
  const int wr = (w >> 1) * 64, wc = (w & 1) * 64;
  const int m0 = blockIdx.x * 128;
  const int seg = blockIdx.y >> 3;
  const int n0 = (blockIdx.y & 7) * 128;
  const unsigned short* Bt = (seg == 0) ? Wq : ((seg == 1) ? Wk : Wv);

  // staging: row = lane>>3 (8 rows/wave/instr), 16B chunk = lane&7; 4 instr -> 32 rows/wave
  const unsigned short* gA = A  + (size_t)(m0 + w*32 + (lane >> 3)) * D_ + (lane & 7) * 8;
  const unsigned short* gB = Bt + (size_t)(n0 + w*32 + (lane >> 3)) * D_ + (lane & 7) * 8;
  unsigned short* lA = ldsA + (w*32)*64;
  unsigned short* lB = ldsB + (w*32)*64;

  f32x4 acc[4][4] = {};

  for (int k0 = 0; k0 < D_; k0 += 64) {
    __syncthreads();
#pragma unroll
    for (int g = 0; g < 4; ++g) {
      async_copy16(gA + (size_t)k0 + (size_t)g*8*D_, lA + g*8*64);
      async_copy16(gB + (size_t)k0 + (size_t)g*8*D_, lB + g*8*64);
    }
    __syncthreads();
#pragma unroll
    for (int ks = 0; ks < 2; ++ks) {
      short8 af[4], bfr[4];
#pragma unroll
      for (int t = 0; t < 4; ++t) {
        af[t]  = *reinterpret_cast<const short8*>(ldsA + (wr + t*16 + l16)*64 + ks*32 + quad*8);
        bfr[t] = *reinterpret_cast<const short8*>(ldsB + (wc + t*16 + l16)*64 + ks*32 + quad*8);
      }
#pragma unroll
      for (int i = 0; i < 4; ++i)
#pragma unroll
        for (int j = 0; j < 4; ++j)
          acc[i][j] = mfma32(af[i], bfr[j], acc[i][j]);
    }
  }

#pragma unroll
  for (int i = 0; i < 4; ++i) {
#pragma unroll
    for (int j = 0; j < 4; ++j) {
      if (seg == 2) {
        const int colc = n0 + wc + j*16 + l16;
        const int hh = colc >> 6, dd = colc & (DH_ - 1);
        const int row0 = m0 + wr + i*16 + quad*4;
        const int bb = row0 >> 11, t0 = row0 & (T_ - 1);
        half4f vh = {(_Float16)acc[i][j][0], (_Float16)acc[i][j][1],
                     (_Float16)acc[i][j][2], (_Float16)acc[i][j][3]};
        *reinterpret_cast<half4f*>(
            &Vo[(size_t)((bb*H_ + hh)*DH_ + dd)*T_ + t0]) = vh;
      } else {
        unsigned short* out = (seg == 0) ? Qo : Ko;
        const float scl = (seg == 0) ? (0.125f * 1.44269504089f) : 1.f;
#pragma unroll
        for (int r = 0; r < 4; ++r) {
          const int row = m0 + wr + i*16 + quad*4 + r;
          const int col = n0 + wc + j*16 + l16;
          out[(size_t)row * D_ + col] = f2bf(acc[i][j][r] * scl);
        }
      }
    }
  }
}

// ---------------- output GEMM (BK=64): fp32 C = Y @ Wo^T ----------------
__global__ __launch_bounds__(256) void gemm_out(
    const unsigned short* __restrict__ A,
    const unsigned short* __restrict__ Bt,
    float* __restrict__ Cout) {
  __shared__ __align__(16) unsigned short ldsA[128*64];
  __shared__ __align__(16) unsigned short ldsB[128*64];
  const int tid = threadIdx.x;
  const int w = tid >> 6, lane = tid & 63;
  const int quad = lane >> 4, l16 = lane & 15;
  const int wr = (w >> 1) * 64, wc = (w & 1) * 64;
  const int m0 = blockIdx.x * 128, n0 = blockIdx.y * 128;

  const unsigned short* gA = A  + (size_t)(m0 + w*32 + (lane >> 3)) * D_ + (lane & 7) * 8;
  const unsigned short* gB = Bt + (size_t)(n0 + w*32 + (lane >> 3)) * D_ + (lane & 7) * 8;
  unsigned short* lA = ldsA + (w*32)*64;
  unsigned short* lB = ldsB + (w*32)*64;

  f32x4 acc[4][4] = {};
  for (int k0 = 0; k0 < D_; k0 += 64) {
    __syncthreads();
#pragma unroll
    for (int g = 0; g < 4; ++g) {
      async_copy16(gA + (size_t)k0 + (size_t)g*8*D_, lA + g*8*64);
      async_copy16(gB + (size_t)k0 + (size_t)g*8*D_, lB + g*8*64);
    }
    __syncthreads();
#pragma unroll
    for (int ks = 0; ks < 2; ++ks) {
      short8 af[4], bfr[4];
#pragma unroll
      for (int t = 0; t < 4; ++t) {
        af[t]  = *reinterpret_cast<const short8*>(ldsA + (wr + t*16 + l16)*64 + ks*32 + quad*8);
        bfr[t] = *reinterpret_cast<const short8*>(ldsB + (wc + t*16 + l16)*64 + ks*32 + quad*8);
      }
#pragma unroll
      for (int i = 0; i < 4; ++i)
#pragma unroll
        for (int j = 0; j < 4; ++j)
          acc[i][j] = mfma32(af[i], bfr[j], acc[i][j]);
    }
  }
#pragma unroll
  for (int i = 0; i < 4; ++i)
#pragma unroll
    for (int j = 0; j < 4; ++j)
#pragma unroll
      for (int r = 0; r < 4; ++r)
        Cout[(size_t)(m0 + wr + i*16 + quad*4 + r) * D_ + n0 + wc + j*16 + l16] =
            acc[i][j][r];
}

// ---------------- causal flash attention (S^T, fused tile pair) ----------------
// R7 kernel, unchanged (passed at <70 us). grid (64=b*H+h, 16=px).
__device__ __forceinline__ half4f score_exp(short8 ka0, short8 ka1,
                                            short8 bq0, short8 bq1,
                                            bool dmask, int kvb, int qrel,
                                            f32x4* osum, half4f vones) {
  f32x4 z = {0.f, 0.f, 0.f, 0.f};
  z = mfma32(ka0, bq0, z);
  z = mfma32(ka1, bq1, z);
  float p0 = __builtin_amdgcn_exp2f(z[0]);
  float p1 = __builtin_amdgcn_exp2f(z[1]);
  float p2 = __builtin_amdgcn_exp2f(z[2]);
  float p3 = __builtin_amdgcn_exp2f(z[3]);
  if (dmask) {               // diag kv-unit: zero where kv > q
    if (kvb + 0 > qrel) p0 = 0.f;
    if (kvb + 1 > qrel) p1 = 0.f;
    if (kvb + 2 > qrel) p2 = 0.f;
    if (kvb + 3 > qrel) p3 = 0.f;
  }
  union { h2raw h2[2]; half4f h4; } u;
  u.h2[0] = __builtin_amdgcn_cvt_pkrtz(p0, p1);
  u.h2[1] = __builtin_amdgcn_cvt_pkrtz(p2, p3);
  *osum = mfma16h(vones, u.h4, *osum);
  return u.h4;
}

__global__ __launch_bounds__(256, 4) void flash_attn(
    const unsigned short* __restrict__ Q,   // (M,D) bf16, pre-scaled
    const unsigned short* __restrict__ K,   // (M,D) bf16
    const _Float16* __restrict__ Vt,        // (B,H,DH,T) f16
    unsigned short* __restrict__ Y) {       // (M,D) bf16
  __shared__ __align__(16) unsigned short Kl[2][64*KP];  // 18.0 KB
  __shared__ __align__(16) _Float16      Vl[2][64*KP];   // 18.0 KB
  const int bh = blockIdx.x, px = blockIdx.y;
  const int h = bh & (H_ - 1), b = bh >> 4;
  const int tid = threadIdx.x;
  const int w = tid >> 6, lane = tid & 63, quad = lane >> 4, l16 = lane & 15;
  const int hc = h * DH_;
  const int itA = px, itB = 31 - px;       // A strictly shallower than B
  const int qgA = itA*64 + w*16, qgB = itB*64 + w*16;
  const int ktmax = itB;

  const int sr = tid >> 2, sc = tid & 3;
  const unsigned short* Kg0 = K + ((size_t)(b*T_) + sr) * D_ + hc + sc*16;
  const _Float16*       Vg0 = Vt + ((size_t)bh * DH_ + sr) * T_ + sc*16;

  uint4 kr0, kr1, vr0, vr1;
  auto loadKV = [&](int kt) {
    const unsigned short* kg = Kg0 + (size_t)kt * 64 * D_;
    const _Float16*       vg = Vg0 + kt * 64;
    kr0 = *reinterpret_cast<const uint4*>(kg);
    kr1 = *reinterpret_cast<const uint4*>(kg + 8);
    vr0 = *reinterpret_cast<const uint4*>(vg);
    vr1 = *reinterpret_cast<const uint4*>(vg + 8);
  };
  auto writeKV = [&](int bi) {
    *reinterpret_cast<uint4*>(&Kl[bi][sr*KP + sc*16])     = kr0;
    *reinterpret_cast<uint4*>(&Kl[bi][sr*KP + sc*16 + 8]) = kr1;
    *reinterpret_cast<uint4*>(&Vl[bi][sr*KP + sc*16])     = vr0;
    *reinterpret_cast<uint4*>(&Vl[bi][sr*KP + sc*16 + 8]) = vr1;
  };

  short8 bqA0, bqA1, bqB0, bqB1;
  bqA0 = *reinterpret_cast<const short8*>(
      Q + (size_t)(b*T_ + qgA + l16) * D_ + hc + quad*8);
  bqA1 = *reinterpret_cast<const short8*>(
      Q + (size_t)(b*T_ + qgA + l16) * D_ + hc + 32 + quad*8);
  bqB0 = *reinterpret_cast<const short8*>(
      Q + (size_t)(b*T_ + qgB + l16) * D_ + hc + quad*8);
  bqB1 = *reinterpret_cast<const short8*>(
      Q + (size_t)(b*T_ + qgB + l16) * D_ + hc + 32 + quad*8);

  f32x4 oA[4] = {}, oB[4] = {};
  f32x4 osA = {}, osB = {};
  const half4f vones = {(_Float16)1.f, (_Float16)1.f, (_Float16)1.f, (_Float16)1.f};
  const int qrelW = w*16 + l16;            // wave-row relative to own diag tile

  loadKV(0);
  writeKV(0);
  __syncthreads();

  for (int kt = 0; kt <= ktmax; ++kt) {
    const int cur = kt & 1;
    if (kt < ktmax) loadKV(kt + 1);        // prefetch overlaps compute
    const bool aOn   = (kt <= px);
    const bool aDiag = (kt == px);
    const bool bDiag = (kt == ktmax);
    const int smax = bDiag ? w : 3;        // 4 waves x 16 q-rows -> bound is w
    for (int s = 0; s <= smax; ++s) {
      const short8 ka0 = *reinterpret_cast<const short8*>(
          &Kl[cur][(s*16 + l16)*KP + quad*8]);
      const short8 ka1 = *reinterpret_cast<const short8*>(
          &Kl[cur][(s*16 + l16)*KP + 32 + quad*8]);
      const int kvb = s*16 + quad*4;
      half4f pfA;
      if (aOn) pfA = score_exp(ka0, ka1, bqA0, bqA1, aDiag, kvb, qrelW, &osA, vones);
      const half4f pfB = score_exp(ka0, ka1, bqB0, bqB1, bDiag, kvb, qrelW, &osB, vones);
#pragma unroll
      for (int dt = 0; dt < 4; ++dt) {
        const half4f vf = *reinterpret_cast<const half4f*>(
            &Vl[cur][(dt*16 + l16)*KP + s*16 + quad*4]);
        if (aOn) oA[dt] = mfma16h(vf, pfA, oA[dt]);
        oB[dt] = mfma16h(vf, pfB, oB[dt]);
      }
    }
    if (kt < ktmax) {
      __syncthreads();
      writeKV(cur ^ 1);
      __syncthreads();
    }
  }

  const float invA = 1.f / osA[0];
  const float invB = 1.f / osB[0];
#pragma unroll
  for (int dt = 0; dt < 4; ++dt) {
    u16x4 ya, yb;
    ya.x = f2bf(oA[dt][0] * invA); ya.y = f2bf(oA[dt][1] * invA);
    ya.z = f2bf(oA[dt][2] * invA); ya.w = f2bf(oA[dt][3] * invA);
    yb.x = f2bf(oB[dt][0] * invB); yb.y = f2bf(oB[dt][1] * invB);
    yb.z = f2bf(oB[dt][2] * invB); yb.w = f2bf(oB[dt][3] * invB);
    *reinterpret_cast<u16x4*>(
        &Y[(size_t)(b*T_ + qgA + l16) * D_ + hc + dt*16 + quad*4]) = ya;
    *reinterpret_cast<u16x4*>(
        &Y[(size_t)(b*T_ + qgB + l16) * D_ + hc + dt*16 + quad*4]) = yb;
  }
}

extern "C" void kernel_launch(void* const* d_in, const int* in_sizes, int n_in,
                              void* d_out, int out_size, void* d_ws, size_t ws_size,
                              hipStream_t stream) {
  const float* x  = (const float*)d_in[0];
  const float* wq = (const float*)d_in[1];
  const float* wk = (const float*)d_in[2];
  const float* wv = (const float*)d_in[3];
  const float* wo = (const float*)d_in[4];

  unsigned short* xb  = (unsigned short*)d_ws;
  unsigned short* wqb = xb  + (size_t)M_ * D_;
  unsigned short* wkb = wqb + (size_t)D_ * D_;
  unsigned short* wvb = wkb + (size_t)D_ * D_;
  unsigned short* wob = wvb + (size_t)D_ * D_;
  unsigned short* q   = wob + (size_t)D_ * D_;
  unsigned short* k   = q   + (size_t)M_ * D_;
  _Float16*       vt  = (_Float16*)(k + (size_t)M_ * D_);
  unsigned short* y   = (unsigned short*)(vt + (size_t)M_ * D_);

  const int ncv = (NX4 + 4*NW4 + 255) / 256;
  cvt_all<<<ncv, 256, 0, stream>>>(x, wq, wk, wv, wo, xb, wqb, wkb, wvb, wob);

  gemm_qkv<<<dim3(M_ / 128, 24), 256, 0, stream>>>(xb, wqb, wkb, wvb, q, k, vt);

  flash_attn<<<dim3(64, 16), 256, 0, stream>>>(q, k, vt, y);

  gemm_out<<<dim3(M_ / 128, D_ / 128), 256, 0, stream>>>(y, wob, (float*)d_out);
}

// Round 10
// 233.457 us; speedup vs baseline: 1.0895x; 1.0895x over previous
//
#include <hip/hip_runtime.h>

#define B_ 4
#define T_ 2048
#define D_ 1024
#define H_ 16
#define DH_ 64
#define M_ (B_*T_)   // 8192 tokens
#define KP 72        // padded LDS row stride (elements) for flash K/V tiles

typedef __attribute__((ext_vector_type(8))) short short8;       // 8 bf16 (MFMA K=32 A/B frag)
typedef __attribute__((ext_vector_type(4))) float f32x4;        // MFMA C/D frag
typedef __attribute__((ext_vector_type(4))) unsigned short u16x4;
typedef _Float16 half4f __attribute__((ext_vector_type(4)));    // MFMA K=16 f16 A/B frag
typedef __fp16 h2raw __attribute__((ext_vector_type(2)));       // cvt_pkrtz return type

__device__ __forceinline__ unsigned short f2bf(float f) {
  unsigned int u = __float_as_uint(f);
  u += 0x7FFFu + ((u >> 16) & 1u);   // RNE
  return (unsigned short)(u >> 16);
}

__device__ __forceinline__ void async_copy16(const void* g, void* l) {
  __builtin_amdgcn_global_load_lds(
      (const __attribute__((address_space(1))) unsigned int*)(g),
      (__attribute__((address_space(3))) unsigned int*)(l),
      16, 0, 0);
}

__device__ __forceinline__ f32x4 mfma32(short8 a, short8 b, f32x4 c) {
  return __builtin_amdgcn_mfma_f32_16x16x32_bf16(a, b, c, 0, 0, 0);
}
__device__ __forceinline__ f32x4 mfma16h(half4f a, half4f b, f32x4 c) {
  return __builtin_amdgcn_mfma_f32_16x16x16f16(a, b, c, 0, 0, 0);
}

// ---------------- fused fp32 -> bf16 convert (x + 4 weights, one launch) ----------------
#define NX4 (M_*D_/4)
#define NW4 (D_*D_/4)
__global__ __launch_bounds__(256) void cvt_all(
    const float* __restrict__ x,  const float* __restrict__ wq,
    const float* __restrict__ wk, const float* __restrict__ wv,
    const float* __restrict__ wo, unsigned short* __restrict__ xb,
    unsigned short* __restrict__ wqb, unsigned short* __restrict__ wkb,
    unsigned short* __restrict__ wvb, unsigned short* __restrict__ wob) {
  int i = blockIdx.x * 256 + threadIdx.x;
  const float* src; unsigned short* dst; int off;
  if (i < NX4)             { src = x;  dst = xb;  off = i; }
  else if (i < NX4 + NW4)  { src = wq; dst = wqb; off = i - NX4; }
  else if (i < NX4 + 2*NW4){ src = wk; dst = wkb; off = i - NX4 - NW4; }
  else if (i < NX4 + 3*NW4){ src = wv; dst = wvb; off = i - NX4 - 2*NW4; }
  else                     { src = wo; dst = wob; off = i - NX4 - 3*NW4; }
  const float4 v = reinterpret_cast<const float4*>(src)[off];
  u16x4 o;
  o.x = f2bf(v.x); o.y = f2bf(v.y); o.z = f2bf(v.z); o.w = f2bf(v.w);
  reinterpret_cast<u16x4*>(dst)[off] = o;
}

// ---------------- fused QKV projection GEMM (BK=64, XOR-swizzled LDS) ----------------
// BK=64 halves the per-iter barrier drains vs BK=32 (16 for K=1024). Row stride
// 128B == 32 banks would make every unswizzled b128 read hit one 4-bank group
// (R8: 3x conflicts). Fix: lane fetches GLOBAL chunk (lane&7)^(lane>>3), so
// LDS[r][j] = global chunk j^(r%8); readers use chunk c^(l16&7) -> uniform
// 8 lanes/4-bank group (b128 structural minimum). Write side stays contiguous
// for global_load_lds.
__global__ __launch_bounds__(256) void gemm_qkv(
    const unsigned short* __restrict__ A,
    const unsigned short* __restrict__ Wq,
    const unsigned short* __restrict__ Wk,
    const unsigned short* __restrict__ Wv,
    unsigned short* __restrict__ Qo,
    unsigned short* __restrict__ Ko,
    _Float16* __restrict__ Vo) {
  __shared__ __align__(16) unsigned short ldsA[128*64];  // 16 KB
  __shared__ __align__(16) unsigned short ldsB[128*64];  // 16 KB
  const int tid = threadIdx.x;
  const int w = tid >> 6, lane = tid & 63;
  const int quad = lane >> 4, l16 = lane & 15;
  const int wr = (w >> 1) * 64, wc = (w & 1) * 64;
  const int m0 = blockIdx.x * 128;
  const int seg = blockIdx.y >> 3;
  const int n0 = (blockIdx.y & 7) * 128;
  const unsigned short* Bt = (seg == 0) ? Wq : ((seg == 1) ? Wk : Wv);

  // staging: row = lane>>3, swizzled global chunk = (lane&7)^(lane>>3)
  const int srow = lane >> 3, schk = (lane & 7) ^ (lane >> 3);
  const unsigned short* gA = A  + (size_t)(m0 + w*32 + srow) * D_ + schk * 8;
  const unsigned short* gB = Bt + (size_t)(n0 + w*32 + srow) * D_ + schk * 8;
  unsigned short* lA = ldsA + (w*32)*64;
  unsigned short* lB = ldsB + (w*32)*64;

  f32x4 acc[4][4] = {};

  for (int k0 = 0; k0 < D_; k0 += 64) {
    __syncthreads();
#pragma unroll
    for (int g = 0; g < 4; ++g) {
      async_copy16(gA + (size_t)k0 + (size_t)g*8*D_, lA + g*8*64);
      async_copy16(gB + (size_t)k0 + (size_t)g*8*D_, lB + g*8*64);
    }
    __syncthreads();
#pragma unroll
    for (int ks = 0; ks < 2; ++ks) {
      short8 af[4], bfr[4];
      const int swz = l16 & 7;
#pragma unroll
      for (int t = 0; t < 4; ++t) {
        const int cA = ((ks*4 + quad) ^ swz) * 8;   // swizzled chunk offset
        af[t]  = *reinterpret_cast<const short8*>(ldsA + (wr + t*16 + l16)*64 + cA);
        bfr[t] = *reinterpret_cast<const short8*>(ldsB + (wc + t*16 + l16)*64 + cA);
      }
#pragma unroll
      for (int i = 0; i < 4; ++i)
#pragma unroll
        for (int j = 0; j < 4; ++j)
          acc[i][j] = mfma32(af[i], bfr[j], acc[i][j]);
    }
  }

#pragma unroll
  for (int i = 0; i < 4; ++i) {
#pragma unroll
    for (int j = 0; j < 4; ++j) {
      if (seg == 2) {
        const int colc = n0 + wc + j*16 + l16;
        const int hh = colc >> 6, dd = colc & (DH_ - 1);
        const int row0 = m0 + wr + i*16 + quad*4;
        const int bb = row0 >> 11, t0 = row0 & (T_ - 1);
        half4f vh = {(_Float16)acc[i][j][0], (_Float16)acc[i][j][1],
                     (_Float16)acc[i][j][2], (_Float16)acc[i][j][3]};
        *reinterpret_cast<half4f*>(
            &Vo[(size_t)((bb*H_ + hh)*DH_ + dd)*T_ + t0]) = vh;
      } else {
        unsigned short* out = (seg == 0) ? Qo : Ko;
        const float scl = (seg == 0) ? (0.125f * 1.44269504089f) : 1.f;
#pragma unroll
        for (int r = 0; r < 4; ++r) {
          const int row = m0 + wr + i*16 + quad*4 + r;
          const int col = n0 + wc + j*16 + l16;
          out[(size_t)row * D_ + col] = f2bf(acc[i][j][r] * scl);
        }
      }
    }
  }
}

// ---------------- output GEMM (BK=64, XOR-swizzled): fp32 C = Y @ Wo^T ----------------
__global__ __launch_bounds__(256) void gemm_out(
    const unsigned short* __restrict__ A,
    const unsigned short* __restrict__ Bt,
    float* __restrict__ Cout) {
  __shared__ __align__(16) unsigned short ldsA[128*64];
  __shared__ __align__(16) unsigned short ldsB[128*64];
  const int tid = threadIdx.x;
  const int w = tid >> 6, lane = tid & 63;
  const int quad = lane >> 4, l16 = lane & 15;
  const int wr = (w >> 1) * 64, wc = (w & 1) * 64;
  const int m0 = blockIdx.x * 128, n0 = blockIdx.y * 128;

  const int srow = lane >> 3, schk = (lane & 7) ^ (lane >> 3);
  const unsigned short* gA = A  + (size_t)(m0 + w*32 + srow) * D_ + schk * 8;
  const unsigned short* gB = Bt + (size_t)(n0 + w*32 + srow) * D_ + schk * 8;
  unsigned short* lA = ldsA + (w*32)*64;
  unsigned short* lB = ldsB + (w*32)*64;

  f32x4 acc[4][4] = {};
  for (int k0 = 0; k0 < D_; k0 += 64) {
    __syncthreads();
#pragma unroll
    for (int g = 0; g < 4; ++g) {
      async_copy16(gA + (size_t)k0 + (size_t)g*8*D_, lA + g*8*64);
      async_copy16(gB + (size_t)k0 + (size_t)g*8*D_, lB + g*8*64);
    }
    __syncthreads();
#pragma unroll
    for (int ks = 0; ks < 2; ++ks) {
      short8 af[4], bfr[4];
      const int swz = l16 & 7;
#pragma unroll
      for (int t = 0; t < 4; ++t) {
        const int cA = ((ks*4 + quad) ^ swz) * 8;
        af[t]  = *reinterpret_cast<const short8*>(ldsA + (wr + t*16 + l16)*64 + cA);
        bfr[t] = *reinterpret_cast<const short8*>(ldsB + (wc + t*16 + l16)*64 + cA);
      }
#pragma unroll
      for (int i = 0; i < 4; ++i)
#pragma unroll
        for (int j = 0; j < 4; ++j)
          acc[i][j] = mfma32(af[i], bfr[j], acc[i][j]);
    }
  }
#pragma unroll
  for (int i = 0; i < 4; ++i)
#pragma unroll
    for (int j = 0; j < 4; ++j)
#pragma unroll
      for (int r = 0; r < 4; ++r)
        Cout[(size_t)(m0 + wr + i*16 + quad*4 + r) * D_ + n0 + wc + j*16 + l16] =
            acc[i][j][r];
}

// ---------------- causal flash attention (S^T, fused tile pair) ----------------
// R7 kernel, unchanged. grid (64=b*H+h, 16=px).
__device__ __forceinline__ half4f score_exp(short8 ka0, short8 ka1,
                                            short8 bq0, short8 bq1,
                                            bool dmask, int kvb, int qrel,
                                            f32x4* osum, half4f vones) {
  f32x4 z = {0.f, 0.f, 0.f, 0.f};
  z = mfma32(ka0, bq0, z);
  z = mfma32(ka1, bq1, z);
  float p0 = __builtin_amdgcn_exp2f(z[0]);
  float p1 = __builtin_amdgcn_exp2f(z[1]);
  float p2 = __builtin_amdgcn_exp2f(z[2]);
  float p3 = __builtin_amdgcn_exp2f(z[3]);
  if (dmask) {               // diag kv-unit: zero where kv > q
    if (kvb + 0 > qrel) p0 = 0.f;
    if (kvb + 1 > qrel) p1 = 0.f;
    if (kvb + 2 > qrel) p2 = 0.f;
    if (kvb + 3 > qrel) p3 = 0.f;
  }
  union { h2raw h2[2]; half4f h4; } u;
  u.h2[0] = __builtin_amdgcn_cvt_pkrtz(p0, p1);
  u.h2[1] = __builtin_amdgcn_cvt_pkrtz(p2, p3);
  *osum = mfma16h(vones, u.h4, *osum);
  return u.h4;
}

__global__ __launch_bounds__(256, 4) void flash_attn(
    const unsigned short* __restrict__ Q,   // (M,D) bf16, pre-scaled
    const unsigned short* __restrict__ K,   // (M,D) bf16
    const _Float16* __restrict__ Vt,        // (B,H,DH,T) f16
    unsigned short* __restrict__ Y) {       // (M,D) bf16
  __shared__ __align__(16) unsigned short Kl[2][64*KP];  // 18.0 KB
  __shared__ __align__(16) _Float16      Vl[2][64*KP];   // 18.0 KB
  const int bh = blockIdx.x, px = blockIdx.y;
  const int h = bh & (H_ - 1), b = bh >> 4;
  const int tid = threadIdx.x;
  const int w = tid >> 6, lane = tid & 63, quad = lane >> 4, l16 = lane & 15;
  const int hc = h * DH_;
  const int itA = px, itB = 31 - px;       // A strictly shallower than B
  const int qgA = itA*64 + w*16, qgB = itB*64 + w*16;
  const int ktmax = itB;

  const int sr = tid >> 2, sc = tid & 3;
  const unsigned short* Kg0 = K + ((size_t)(b*T_) + sr) * D_ + hc + sc*16;
  const _Float16*       Vg0 = Vt + ((size_t)bh * DH_ + sr) * T_ + sc*16;

  uint4 kr0, kr1, vr0, vr1;
  auto loadKV = [&](int kt) {
    const unsigned short* kg = Kg0 + (size_t)kt * 64 * D_;
    const _Float16*       vg = Vg0 + kt * 64;
    kr0 = *reinterpret_cast<const uint4*>(kg);
    kr1 = *reinterpret_cast<const uint4*>(kg + 8);
    vr0 = *reinterpret_cast<const uint4*>(vg);
    vr1 = *reinterpret_cast<const uint4*>(vg + 8);
  };
  auto writeKV = [&](int bi) {
    *reinterpret_cast<uint4*>(&Kl[bi][sr*KP + sc*16])     = kr0;
    *reinterpret_cast<uint4*>(&Kl[bi][sr*KP + sc*16 + 8]) = kr1;
    *reinterpret_cast<uint4*>(&Vl[bi][sr*KP + sc*16])     = vr0;
    *reinterpret_cast<uint4*>(&Vl[bi][sr*KP + sc*16 + 8]) = vr1;
  };

  short8 bqA0, bqA1, bqB0, bqB1;
  bqA0 = *reinterpret_cast<const short8*>(
      Q + (size_t)(b*T_ + qgA + l16) * D_ + hc + quad*8);
  bqA1 = *reinterpret_cast<const short8*>(
      Q + (size_t)(b*T_ + qgA + l16) * D_ + hc + 32 + quad*8);
  bqB0 = *reinterpret_cast<const short8*>(
      Q + (size_t)(b*T_ + qgB + l16) * D_ + hc + quad*8);
  bqB1 = *reinterpret_cast<const short8*>(
      Q + (size_t)(b*T_ + qgB + l16) * D_ + hc + 32 + quad*8);

  f32x4 oA[4] = {}, oB[4] = {};
  f32x4 osA = {}, osB = {};
  const half4f vones = {(_Float16)1.f, (_Float16)1.f, (_Float16)1.f, (_Float16)1.f};
  const int qrelW = w*16 + l16;            // wave-row relative to own diag tile

  loadKV(0);
  writeKV(0);
  __syncthreads();

  for (int kt = 0; kt <= ktmax; ++kt) {
    const int cur = kt & 1;
    if (kt < ktmax) loadKV(kt + 1);        // prefetch overlaps compute
    const bool aOn   = (kt <= px);
    const bool aDiag = (kt == px);
    const bool bDiag = (kt == ktmax);
    const int smax = bDiag ? w : 3;        // 4 waves x 16 q-rows -> bound is w
    for (int s = 0; s <= smax; ++s) {
      const short8 ka0 = *reinterpret_cast<const short8*>(
          &Kl[cur][(s*16 + l16)*KP + quad*8]);
      const short8 ka1 = *reinterpret_cast<const short8*>(
          &Kl[cur][(s*16 + l16)*KP + 32 + quad*8]);
      const int kvb = s*16 + quad*4;
      half4f pfA;
      if (aOn) pfA = score_exp(ka0, ka1, bqA0, bqA1, aDiag, kvb, qrelW, &osA, vones);
      const half4f pfB = score_exp(ka0, ka1, bqB0, bqB1, bDiag, kvb, qrelW, &osB, vones);
#pragma unroll
      for (int dt = 0; dt < 4; ++dt) {
        const half4f vf = *reinterpret_cast<const half4f*>(
            &Vl[cur][(dt*16 + l16)*KP + s*16 + quad*4]);
        if (aOn) oA[dt] = mfma16h(vf, pfA, oA[dt]);
        oB[dt] = mfma16h(vf, pfB, oB[dt]);
      }
    }
    if (kt < ktmax) {
      __syncthreads();
      writeKV(cur ^ 1);
      __syncthreads();
    }
  }

  const float invA = 1.f / osA[0];
  const float invB = 1.f / osB[0];
#pragma unroll
  for (int dt = 0; dt < 4; ++dt) {
    u16x4 ya, yb;
    ya.x = f2bf(oA[dt][0] * invA); ya.y = f2bf(oA[dt][1] * invA);
    ya.z = f2bf(oA[dt][2] * invA); ya.w = f2bf(oA[dt][3] * invA);
    yb.x = f2bf(oB[dt][0] * invB); yb.y = f2bf(oB[dt][1] * invB);
    yb.z = f2bf(oB[dt][2] * invB); yb.w = f2bf(oB[dt][3] * invB);
    *reinterpret_cast<u16x4*>(
        &Y[(size_t)(b*T_ + qgA + l16) * D_ + hc + dt*16 + quad*4]) = ya;
    *reinterpret_cast<u16x4*>(
        &Y[(size_t)(b*T_ + qgB + l16) * D_ + hc + dt*16 + quad*4]) = yb;
  }
}

extern "C" void kernel_launch(void* const* d_in, const int* in_sizes, int n_in,
                              void* d_out, int out_size, void* d_ws, size_t ws_size,
                              hipStream_t stream) {
  const float* x  = (const float*)d_in[0];
  const float* wq = (const float*)d_in[1];
  const float* wk = (const float*)d_in[2];
  const float* wv = (const float*)d_in[3];
  const float* wo = (const float*)d_in[4];

  unsigned short* xb  = (unsigned short*)d_ws;
  unsigned short* wqb = xb  + (size_t)M_ * D_;
  unsigned short* wkb = wqb + (size_t)D_ * D_;
  unsigned short* wvb = wkb + (size_t)D_ * D_;
  unsigned short* wob = wvb + (size_t)D_ * D_;
  unsigned short* q   = wob + (size_t)D_ * D_;
  unsigned short* k   = q   + (size_t)M_ * D_;
  _Float16*       vt  = (_Float16*)(k + (size_t)M_ * D_);
  unsigned short* y   = (unsigned short*)(vt + (size_t)M_ * D_);

  const int ncv = (NX4 + 4*NW4 + 255) / 256;
  cvt_all<<<ncv, 256, 0, stream>>>(x, wq, wk, wv, wo, xb, wqb, wkb, wvb, wob);

  gemm_qkv<<<dim3(M_ / 128, 24), 256, 0, stream>>>(xb, wqb, wkb, wvb, q, k, vt);

  flash_attn<<<dim3(64, 16), 256, 0, stream>>>(q, k, vt, y);

  gemm_out<<<dim3(M_ / 128, D_ / 128), 256, 0, stream>>>(y, wob, (float*)d_out);
}